// Round 5
// baseline (235.419 us; speedup 1.0000x reference)
//
#include <hip/hip_runtime.h>
#include <hip/hip_bf16.h>

#define T_TOK 4096
#define H_DIM 1024
#define E_NUM 8
#define I_DIM 1024
#define PAD_CAP 9216   // 72 * 128 >= 8192 + 8*127
#define RBLK 16        // router blocks (256 tokens each)
#define G1_ROWBLK (PAD_CAP / 128)   // 72

typedef __attribute__((ext_vector_type(4))) float f32x4;
typedef __attribute__((ext_vector_type(8))) short bf16x8;

__device__ __forceinline__ unsigned short f2b(float f) {
  union { float f; unsigned int u; } v; v.f = f;
  unsigned int r = v.u + 0x7fffu + ((v.u >> 16) & 1u);  // RNE to bf16
  return (unsigned short)(r >> 16);
}

__device__ __forceinline__ void async_copy16(const void* g, void* l) {
  __builtin_amdgcn_global_load_lds(
      (const __attribute__((address_space(1))) void*)g,
      (__attribute__((address_space(3))) void*)l, 16, 0, 0);
}

// 2048-float f32->bf16 chunk conversion (256 threads x 8)
__device__ __forceinline__ void conv_chunk(const float* __restrict__ src,
                                           unsigned short* __restrict__ dst,
                                           size_t base) {
  size_t i = base + (size_t)threadIdx.x * 8;
  float4 f0 = *(const float4*)(src + i);
  float4 f1 = *(const float4*)(src + i + 4);
  uint4 pk;
  pk.x = (unsigned)f2b(f0.x) | ((unsigned)f2b(f0.y) << 16);
  pk.y = (unsigned)f2b(f0.z) | ((unsigned)f2b(f0.w) << 16);
  pk.z = (unsigned)f2b(f1.x) | ((unsigned)f2b(f1.y) << 16);
  pk.w = (unsigned)f2b(f1.z) | ((unsigned)f2b(f1.w) << 16);
  *(uint4*)(dst + i) = pk;
}

// ---------------- prep: routing (16 blk) + x/w13 conv + out-zeroing ------------
// Streams at ~6.4 TB/s (measured via round-1->2 delta) — HBM roofline.
// w2 conversion rides in gemm1's grid tail. Blocks 10256..12303 zero `out`
// (16 MB) so gemm2's fused-combine epilogue can atomicAdd into it.
__global__ __launch_bounds__(256) void k_prep(
    const float* __restrict__ x, const float* __restrict__ logits,
    const float* __restrict__ scale, const float* __restrict__ w13,
    unsigned short* __restrict__ xb, unsigned short* __restrict__ w13b,
    int* __restrict__ tids, float* __restrict__ cw, int* __restrict__ cnt,
    float* __restrict__ out) {
  const int b = blockIdx.x;
  if (b < RBLK) {
    __shared__ int s_cnt[E_NUM];
    const int tid = threadIdx.x;
    if (tid < E_NUM) s_cnt[tid] = 0;
    __syncthreads();
    int t = b * 256 + tid;
    float l[E_NUM];
    *(float4*)(l)     = *(const float4*)(logits + (size_t)t * E_NUM);
    *(float4*)(l + 4) = *(const float4*)(logits + (size_t)t * E_NUM + 4);
    float m = l[0];
#pragma unroll
    for (int i = 1; i < E_NUM; ++i) m = fmaxf(m, l[i]);
    float p[E_NUM]; float s = 0.f;
#pragma unroll
    for (int i = 0; i < E_NUM; ++i) { p[i] = expf(l[i] - m); s += p[i]; }
    int i0 = 0; float b0 = l[0];
#pragma unroll
    for (int i = 1; i < E_NUM; ++i) if (l[i] > b0) { b0 = l[i]; i0 = i; }
    int i1 = -1; float b1 = -1e30f;
#pragma unroll
    for (int i = 0; i < E_NUM; ++i) if (i != i0 && l[i] > b1) { b1 = l[i]; i1 = i; }
    float g0 = p[i0] / s, g1 = p[i1] / s;
    float r = g0 + g1;
    cw[t * 2]     = g0 / r * scale[i0];
    cw[t * 2 + 1] = g1 / r * scale[i1];
    tids[t * 2] = i0; tids[t * 2 + 1] = i1;
    atomicAdd(&s_cnt[i0], 1);
    atomicAdd(&s_cnt[i1], 1);
    __syncthreads();
    if (tid < E_NUM) cnt[b * E_NUM + tid] = s_cnt[tid];
    return;
  }
  const int cb = b - RBLK;
  if (cb < 2048)        conv_chunk(x,   xb,   (size_t)cb * 2048);
  else if (cb < 10240)  conv_chunk(w13, w13b, (size_t)(cb - 2048) * 2048);
  else {
    // zero out[] chunk: 2048 floats
    size_t i = (size_t)(cb - 10240) * 2048 + (size_t)threadIdx.x * 8;
    uint4 z = {0u, 0u, 0u, 0u};
    *(uint4*)(out + i)     = z;
    *(uint4*)(out + i + 4) = z;
  }
}

// ---------------- scatter (fused scan): every block recomputes bases from cnt --
// (inv dropped — gemm2's fused combine uses perm/cw directly)
__global__ __launch_bounds__(256) void k_scatter(
    const int* __restrict__ tids, const int* __restrict__ cnt,
    int* __restrict__ pad_off, int* __restrict__ perm) {
  __shared__ int s_cnt[RBLK * E_NUM];
  __shared__ int s_tot[E_NUM];
  __shared__ int s_off[E_NUM];
  __shared__ int s_base[E_NUM];
  __shared__ int l_cnt[E_NUM];
  const int b = blockIdx.x, tid = threadIdx.x;
  if (tid < RBLK * E_NUM) s_cnt[tid] = cnt[tid];
  if (tid < E_NUM) l_cnt[tid] = 0;
  __syncthreads();
  if (tid < E_NUM) {
    int tot = 0;
#pragma unroll
    for (int bb = 0; bb < RBLK; ++bb) tot += s_cnt[bb * E_NUM + tid];
    s_tot[tid] = tot;
  }
  __syncthreads();
  if (tid < E_NUM) {
    int off = 0;
    for (int e = 0; e < tid; ++e) off += (s_tot[e] + 127) & ~127;
    s_off[tid] = off;
    int myb = off;
    for (int bb = 0; bb < b; ++bb) myb += s_cnt[bb * E_NUM + tid];
    s_base[tid] = myb;
    if (b == 0) {
      pad_off[tid] = off;
      if (tid == E_NUM - 1) pad_off[E_NUM] = off + ((s_tot[tid] + 127) & ~127);
    }
  }
  __syncthreads();
  if (b < E_NUM) {
    int start = s_off[b] + s_tot[b];
    int end   = s_off[b] + ((s_tot[b] + 127) & ~127);
    for (int i = start + tid; i < end; i += 256) perm[i] = -1;
  }
  int t = b * 256 + tid;
  int i0 = tids[t * 2], i1 = tids[t * 2 + 1];
  int r0 = atomicAdd(&l_cnt[i0], 1);
  perm[s_base[i0] + r0] = t * 2;
  int r1 = atomicAdd(&l_cnt[i1], 1);
  perm[s_base[i1] + r1] = t * 2 + 1;
}

// ---------------- GEMM1: h = gelu(x@w1^T) * (x@w3^T) ----------------
// XCD-chunked block remap (round 3, verified: FETCH 84->66 MB): XCD x owns
// row-blocks [9x, 9x+9), sweeping 16 col-blocks locally — pins A in the XCD's
// L2 (16x reuse) and keeps B XCD-local (1 expert slice). by >= 72 = w2
// f32->bf16 conversion tail. __launch_bounds__(256,2): (256,4) regressed. Keep.
// GELU via exp2-sigmoid identity (~3e-4 max err, < bf16 h quantization).
__global__ __launch_bounds__(256, 2) void k_gemm1(
    const unsigned short* __restrict__ xbf,
    const unsigned short* __restrict__ w13b,
    const int* __restrict__ perm, const int* __restrict__ pad_off,
    unsigned short* __restrict__ h_buf,
    const float* __restrict__ w2, unsigned short* __restrict__ w2b) {
  __shared__ __align__(16) unsigned short a_lds[128 * 64];
  __shared__ __align__(16) unsigned short b_lds[128 * 64];
  const int by = blockIdx.y;
  if (by >= G1_ROWBLK) {
    int cb = (by - G1_ROWBLK) * 16 + blockIdx.x;   // 0..4095
    conv_chunk(w2, w2b, (size_t)cb * 2048);
    return;
  }
  const int vid = blockIdx.x + 16 * by;
  const int xcd = vid & 7, j = vid >> 3;          // j in [0,144)
  const int rb  = xcd * 9 + (j >> 4);             // row-block 0..71
  const int cbx = j & 15;                         // col-block 0..15
  const int tid = threadIdx.x;
  const int wave = tid >> 6, lane = tid & 63;
  const int row0 = rb * 128;
  if (row0 >= pad_off[E_NUM]) return;
  int e = 0;
#pragma unroll
  for (int i = 1; i < E_NUM; ++i) if (row0 >= pad_off[i]) e = i;
  const int iBase = cbx * 64;

  const int srcChunk = (lane & 7) ^ ((lane >> 3) & 7);

  const unsigned short* agbase[4];
#pragma unroll
  for (int jj = 0; jj < 4; ++jj) {
    int r = jj * 32 + wave * 8 + (lane >> 3);
    int p = perm[row0 + r];
    int tok = (p < 0) ? 0 : (p >> 1);
    agbase[jj] = xbf + (size_t)tok * H_DIM + srcChunk * 8;
  }
  const unsigned short* bgbase[4];
#pragma unroll
  for (int jj = 0; jj < 4; ++jj) {
    int brow = jj * 32 + wave * 8 + (lane >> 3);
    int seg = brow >> 5, half = seg & 1;
    int col = iBase + (seg >> 1) * 32 + (brow & 31);
    bgbase[jj] = w13b + ((size_t)e * 2 * I_DIM + half * I_DIM + col) * H_DIM + srcChunk * 8;
  }

  f32x4 acc[4][4];
#pragma unroll
  for (int mi = 0; mi < 4; ++mi)
#pragma unroll
    for (int ni = 0; ni < 4; ++ni) acc[mi][ni] = (f32x4)(0.f);

  const int wm = wave >> 1, wn = wave & 1;
  const int ml = lane & 15, quad = lane >> 4;

  for (int k0 = 0; k0 < H_DIM; k0 += 64) {
    __syncthreads();
#pragma unroll
    for (int jj = 0; jj < 4; ++jj)
      async_copy16(agbase[jj] + k0, a_lds + (jj * 256 + wave * 64) * 8);
#pragma unroll
    for (int jj = 0; jj < 4; ++jj)
      async_copy16(bgbase[jj] + k0, b_lds + (jj * 256 + wave * 64) * 8);
    __syncthreads();
#pragma unroll
    for (int ks = 0; ks < 2; ++ks) {
      const int ch = ((ks * 4 + quad) ^ (ml & 7)) * 8;
      bf16x8 af[4], bfr[4];
#pragma unroll
      for (int mi = 0; mi < 4; ++mi)
        af[mi] = *(const bf16x8*)(a_lds + (wm * 64 + mi * 16 + ml) * 64 + ch);
#pragma unroll
      for (int ni = 0; ni < 4; ++ni)
        bfr[ni] = *(const bf16x8*)(b_lds + (wn * 64 + ni * 16 + ml) * 64 + ch);
#pragma unroll
      for (int mi = 0; mi < 4; ++mi)
#pragma unroll
        for (int ni = 0; ni < 4; ++ni)
          acc[mi][ni] = __builtin_amdgcn_mfma_f32_16x16x32_bf16(af[mi], bfr[ni], acc[mi][ni], 0, 0, 0);
    }
  }
#pragma unroll
  for (int mi = 0; mi < 4; ++mi) {
#pragma unroll
    for (int nc = 0; nc < 2; ++nc) {
      f32x4 g = acc[mi][nc];
      f32x4 uu = acc[mi][nc + 2];
#pragma unroll
      for (int r = 0; r < 4; ++r) {
        int row = row0 + wm * 64 + mi * 16 + quad * 4 + r;
        int col = iBase + wn * 32 + nc * 16 + ml;
        float gg = g[r];
        float q  = gg * (2.3022080f + 0.10294324f * gg * gg);
        float z  = __builtin_amdgcn_exp2f(-q);
        float hv = gg * uu[r] * __builtin_amdgcn_rcpf(1.f + z);
        h_buf[(size_t)row * I_DIM + col] = f2b(hv);
      }
    }
  }
}

// ---------------- GEMM2 + fused combine: out[tok] += cw * (h[slot] @ w2[e]^T) ---
// Same XCD-chunked remap as gemm1 (A = h_buf rows L2-pinned, B = w2 slice
// L2-resident). 128x128 tile, __launch_bounds__(256,3): 576 blocks <= 768
// slots, one residency round. Epilogue: instead of writing bf16 y (18.9 MB)
// for a separate combine pass (33.5 MB re-read + 6th kernel), each f32
// accumulator is scaled by cw[perm[row]] and atomicAdd'ed into out[tok][col].
// Each out element receives exactly K=2 contributions from different blocks
// -> negligible contention; 9.4M f32 atomics ~ 38 MB of L2 RMW. Also skips
// the y bf16 quantization (accuracy strictly improves). out pre-zeroed in prep.
// ROUND-4 BUG (fixed): B-fragment read MUST include the wave-column term
// wn*64 — dropping it made wn=1 waves compute cols 0..63 but write 64..127
// (absmax 0.94). Keep `(wn * 64 + ni * 16 + ml)` in sync with the epilogue's
// `cBase + wn * 64 + ni * 16 + ml`.
__global__ __launch_bounds__(256, 3) void k_gemm2(
    const unsigned short* __restrict__ h_buf,
    const unsigned short* __restrict__ w2b,
    const int* __restrict__ pad_off, const int* __restrict__ perm,
    const float* __restrict__ cw,
    float* __restrict__ out) {
  __shared__ __align__(16) unsigned short a_lds[128 * 64];
  __shared__ __align__(16) unsigned short b_lds[128 * 64];
  const int vid = blockIdx.x + 8 * blockIdx.y;    // 0..575
  const int xcd = vid & 7, j = vid >> 3;          // j in [0,72)
  const int rb  = xcd * 9 + (j >> 3);             // row-block 0..71
  const int cbx = j & 7;                          // col-block 0..7
  const int tid = threadIdx.x;
  const int wave = tid >> 6, lane = tid & 63;
  const int row0 = rb * 128;
  if (row0 >= pad_off[E_NUM]) return;
  int e = 0;
#pragma unroll
  for (int i = 1; i < E_NUM; ++i) if (row0 >= pad_off[i]) e = i;
  const int cBase = cbx * 128;
  const int srcChunk = (lane & 7) ^ ((lane >> 3) & 7);

  const unsigned short* agbase[4];
#pragma unroll
  for (int jj = 0; jj < 4; ++jj) {
    int r = jj * 32 + wave * 8 + (lane >> 3);
    agbase[jj] = h_buf + (size_t)(row0 + r) * I_DIM + srcChunk * 8;
  }
  const unsigned short* bgbase[4];
#pragma unroll
  for (int jj = 0; jj < 4; ++jj) {
    int brow = jj * 32 + wave * 8 + (lane >> 3);
    bgbase[jj] = w2b + ((size_t)e * H_DIM + cBase + brow) * I_DIM + srcChunk * 8;
  }
  f32x4 acc[4][4];
#pragma unroll
  for (int mi = 0; mi < 4; ++mi)
#pragma unroll
    for (int ni = 0; ni < 4; ++ni) acc[mi][ni] = (f32x4)(0.f);

  const int wm = wave >> 1, wn = wave & 1;
  const int ml = lane & 15, quad = lane >> 4;

  for (int k0 = 0; k0 < I_DIM; k0 += 64) {
    __syncthreads();
#pragma unroll
    for (int jj = 0; jj < 4; ++jj)
      async_copy16(agbase[jj] + k0, a_lds + (jj * 256 + wave * 64) * 8);
#pragma unroll
    for (int jj = 0; jj < 4; ++jj)
      async_copy16(bgbase[jj] + k0, b_lds + (jj * 256 + wave * 64) * 8);
    __syncthreads();
#pragma unroll
    for (int ks = 0; ks < 2; ++ks) {
      const int ch = ((ks * 4 + quad) ^ (ml & 7)) * 8;
      bf16x8 af[4], bfr[4];
#pragma unroll
      for (int mi = 0; mi < 4; ++mi)
        af[mi] = *(const bf16x8*)(a_lds + (wm * 64 + mi * 16 + ml) * 64 + ch);
#pragma unroll
      for (int ni = 0; ni < 4; ++ni)
        bfr[ni] = *(const bf16x8*)(b_lds + (wn * 64 + ni * 16 + ml) * 64 + ch);
#pragma unroll
      for (int mi = 0; mi < 4; ++mi)
#pragma unroll
        for (int ni = 0; ni < 4; ++ni)
          acc[mi][ni] = __builtin_amdgcn_mfma_f32_16x16x32_bf16(af[mi], bfr[ni], acc[mi][ni], 0, 0, 0);
    }
  }
  // fused combine epilogue
#pragma unroll
  for (int mi = 0; mi < 4; ++mi) {
#pragma unroll
    for (int r = 0; r < 4; ++r) {
      int row = row0 + wm * 64 + mi * 16 + quad * 4 + r;
      int p = perm[row];
      if (p >= 0) {
        float wgt = cw[p];
        int tok = p >> 1;
        float* o = out + (size_t)tok * H_DIM + cBase + wn * 64 + ml;
#pragma unroll
        for (int ni = 0; ni < 4; ++ni)
          atomicAdd(o + ni * 16, wgt * acc[mi][ni][r]);
      }
    }
  }
}

extern "C" void kernel_launch(void* const* d_in, const int* in_sizes, int n_in,
                              void* d_out, int out_size, void* d_ws, size_t ws_size,
                              hipStream_t stream) {
  const float* x      = (const float*)d_in[0];
  const float* logits = (const float*)d_in[1];
  const float* scale  = (const float*)d_in[2];
  const float* w13    = (const float*)d_in[3];
  const float* w2     = (const float*)d_in[4];
  float* out = (float*)d_out;

  char* ws = (char*)d_ws;
  int*   pad_off = (int*)(ws + 128);              // 9 ints
  int*   cnt     = (int*)(ws + 1024);             // RBLK*E ints
  int*   tids    = (int*)(ws + 4096);             // T*2 ints (32 KB)
  float* cw      = (float*)(ws + 65536);          // T*2 floats (32 KB)
  int*   perm    = (int*)(ws + 131072);           // PAD_CAP ints (36 KB)
  unsigned short* xb    = (unsigned short*)(ws + 0x40000);    // 8 MB
  unsigned short* h_buf = (unsigned short*)(ws + 0x900000);   // 18.9 MB
  unsigned short* w13b  = (unsigned short*)(ws + 0x1C00000);  // 32 MB
  unsigned short* w2b   = (unsigned short*)(ws + 0x3C00000);  // 16 MB (total 76 MB)

  // prep: routing (16) + x conv (2048) + w13 conv (8192) + out zeroing (2048)
  k_prep<<<12288 + RBLK, 256, 0, stream>>>(x, logits, scale, w13,
                                           xb, w13b, tids, cw, cnt, out);
  k_scatter<<<RBLK, 256, 0, stream>>>(tids, cnt, pad_off, perm);
  k_gemm1<<<dim3(16, G1_ROWBLK + 256), 256, 0, stream>>>(xb, w13b, perm, pad_off,
                                                         h_buf, w2, w2b);
  k_gemm2<<<dim3(8, PAD_CAP / 128), 256, 0, stream>>>(h_buf, w2b, pad_off,
                                                      perm, cw, out);
}

// Round 7
// 224.149 us; speedup vs baseline: 1.0503x; 1.0503x over previous
//
#include <hip/hip_runtime.h>
#include <hip/hip_bf16.h>

#define T_TOK 4096
#define H_DIM 1024
#define E_NUM 8
#define I_DIM 1024
#define PAD_CAP 9216   // 72 * 128 >= 8192 + 8*127
#define RBLK 16        // router blocks (256 tokens each)
#define G1_ROWBLK (PAD_CAP / 128)   // 72

typedef __attribute__((ext_vector_type(4))) float f32x4;
typedef __attribute__((ext_vector_type(8))) short bf16x8;

__device__ __forceinline__ unsigned short f2b(float f) {
  union { float f; unsigned int u; } v; v.f = f;
  unsigned int r = v.u + 0x7fffu + ((v.u >> 16) & 1u);  // RNE to bf16
  return (unsigned short)(r >> 16);
}

__device__ __forceinline__ void async_copy16(const void* g, void* l) {
  __builtin_amdgcn_global_load_lds(
      (const __attribute__((address_space(1))) void*)g,
      (__attribute__((address_space(3))) void*)l, 16, 0, 0);
}

// 2048-float f32->bf16 chunk conversion (256 threads x 8)
__device__ __forceinline__ void conv_chunk(const float* __restrict__ src,
                                           unsigned short* __restrict__ dst,
                                           size_t base) {
  size_t i = base + (size_t)threadIdx.x * 8;
  float4 f0 = *(const float4*)(src + i);
  float4 f1 = *(const float4*)(src + i + 4);
  uint4 pk;
  pk.x = (unsigned)f2b(f0.x) | ((unsigned)f2b(f0.y) << 16);
  pk.y = (unsigned)f2b(f0.z) | ((unsigned)f2b(f0.w) << 16);
  pk.z = (unsigned)f2b(f1.x) | ((unsigned)f2b(f1.y) << 16);
  pk.w = (unsigned)f2b(f1.z) | ((unsigned)f2b(f1.w) << 16);
  *(uint4*)(dst + i) = pk;
}

// ---------------- prep: blocks 0..15 route-count, 16..10255 f32->bf16 conv ------
// Streams x + w13 at ~HBM roofline. w2 conversion rides in gemm1's grid tail.
// ROUND-5 LESSON: do NOT fuse combine into gemm2 via atomicAdd — 9.4M scattered
// f32 atomics cost ~+20us (1 serialized RMW/element, no cacheline merging),
// plus out-zeroing here (+2.5us). Separate streaming combine is cheaper.
__global__ __launch_bounds__(256) void k_prep(
    const float* __restrict__ x, const float* __restrict__ logits,
    const float* __restrict__ scale, const float* __restrict__ w13,
    unsigned short* __restrict__ xb, unsigned short* __restrict__ w13b,
    int* __restrict__ tids, float* __restrict__ cw, int* __restrict__ cnt) {
  const int b = blockIdx.x;
  if (b < RBLK) {
    __shared__ int s_cnt[E_NUM];
    const int tid = threadIdx.x;
    if (tid < E_NUM) s_cnt[tid] = 0;
    __syncthreads();
    int t = b * 256 + tid;
    float l[E_NUM];
    *(float4*)(l)     = *(const float4*)(logits + (size_t)t * E_NUM);
    *(float4*)(l + 4) = *(const float4*)(logits + (size_t)t * E_NUM + 4);
    float m = l[0];
#pragma unroll
    for (int i = 1; i < E_NUM; ++i) m = fmaxf(m, l[i]);
    float p[E_NUM]; float s = 0.f;
#pragma unroll
    for (int i = 0; i < E_NUM; ++i) { p[i] = expf(l[i] - m); s += p[i]; }
    int i0 = 0; float b0 = l[0];
#pragma unroll
    for (int i = 1; i < E_NUM; ++i) if (l[i] > b0) { b0 = l[i]; i0 = i; }
    int i1 = -1; float b1 = -1e30f;
#pragma unroll
    for (int i = 0; i < E_NUM; ++i) if (i != i0 && l[i] > b1) { b1 = l[i]; i1 = i; }
    float g0 = p[i0] / s, g1 = p[i1] / s;
    float r = g0 + g1;
    cw[t * 2]     = g0 / r * scale[i0];
    cw[t * 2 + 1] = g1 / r * scale[i1];
    tids[t * 2] = i0; tids[t * 2 + 1] = i1;
    atomicAdd(&s_cnt[i0], 1);
    atomicAdd(&s_cnt[i1], 1);
    __syncthreads();
    if (tid < E_NUM) cnt[b * E_NUM + tid] = s_cnt[tid];
    return;
  }
  const int cb = b - RBLK;
  if (cb < 2048) conv_chunk(x,   xb,   (size_t)cb * 2048);
  else           conv_chunk(w13, w13b, (size_t)(cb - 2048) * 2048);
}

// ---------------- scatter (fused scan): every block recomputes bases from cnt --
__global__ __launch_bounds__(256) void k_scatter(
    const int* __restrict__ tids, const int* __restrict__ cnt,
    int* __restrict__ pad_off, int* __restrict__ perm, int* __restrict__ inv) {
  __shared__ int s_cnt[RBLK * E_NUM];
  __shared__ int s_tot[E_NUM];
  __shared__ int s_off[E_NUM];
  __shared__ int s_base[E_NUM];
  __shared__ int l_cnt[E_NUM];
  const int b = blockIdx.x, tid = threadIdx.x;
  if (tid < RBLK * E_NUM) s_cnt[tid] = cnt[tid];
  if (tid < E_NUM) l_cnt[tid] = 0;
  __syncthreads();
  if (tid < E_NUM) {
    int tot = 0;
#pragma unroll
    for (int bb = 0; bb < RBLK; ++bb) tot += s_cnt[bb * E_NUM + tid];
    s_tot[tid] = tot;
  }
  __syncthreads();
  if (tid < E_NUM) {
    int off = 0;
    for (int e = 0; e < tid; ++e) off += (s_tot[e] + 127) & ~127;
    s_off[tid] = off;
    int myb = off;
    for (int bb = 0; bb < b; ++bb) myb += s_cnt[bb * E_NUM + tid];
    s_base[tid] = myb;
    if (b == 0) {
      pad_off[tid] = off;
      if (tid == E_NUM - 1) pad_off[E_NUM] = off + ((s_tot[tid] + 127) & ~127);
    }
  }
  __syncthreads();
  if (b < E_NUM) {
    int start = s_off[b] + s_tot[b];
    int end   = s_off[b] + ((s_tot[b] + 127) & ~127);
    for (int i = start + tid; i < end; i += 256) perm[i] = -1;
  }
  int t = b * 256 + tid;
  int i0 = tids[t * 2], i1 = tids[t * 2 + 1];
  int r0 = atomicAdd(&l_cnt[i0], 1);
  int s0 = s_base[i0] + r0;
  perm[s0] = t * 2; inv[t * 2] = s0;
  int r1 = atomicAdd(&l_cnt[i1], 1);
  int s1 = s_base[i1] + r1;
  perm[s1] = t * 2 + 1; inv[t * 2 + 1] = s1;
}

// ---------------- GEMM1: h = gelu(x@w1^T) * (x@w3^T) ----------------
// XCD-chunked block remap (round 3, verified: FETCH 84->66 MB): XCD x owns
// row-blocks [9x, 9x+9), sweeping 16 col-blocks locally — pins A in the XCD's
// L2 (16x reuse) and keeps B XCD-local (1 expert slice). by >= 72 = w2
// f32->bf16 conversion tail. __launch_bounds__(256,2): (256,4) regressed. Keep.
// GELU via exp2-sigmoid identity (~3e-4 max err, < bf16 h quantization).
__global__ __launch_bounds__(256, 2) void k_gemm1(
    const unsigned short* __restrict__ xbf,
    const unsigned short* __restrict__ w13b,
    const int* __restrict__ perm, const int* __restrict__ pad_off,
    unsigned short* __restrict__ h_buf,
    const float* __restrict__ w2, unsigned short* __restrict__ w2b) {
  __shared__ __align__(16) unsigned short a_lds[128 * 64];
  __shared__ __align__(16) unsigned short b_lds[128 * 64];
  const int by = blockIdx.y;
  if (by >= G1_ROWBLK) {
    int cb = (by - G1_ROWBLK) * 16 + blockIdx.x;   // 0..4095
    conv_chunk(w2, w2b, (size_t)cb * 2048);
    return;
  }
  const int vid = blockIdx.x + 16 * by;
  const int xcd = vid & 7, j = vid >> 3;          // j in [0,144)
  const int rb  = xcd * 9 + (j >> 4);             // row-block 0..71
  const int cbx = j & 15;                         // col-block 0..15
  const int tid = threadIdx.x;
  const int wave = tid >> 6, lane = tid & 63;
  const int row0 = rb * 128;
  if (row0 >= pad_off[E_NUM]) return;
  int e = 0;
#pragma unroll
  for (int i = 1; i < E_NUM; ++i) if (row0 >= pad_off[i]) e = i;
  const int iBase = cbx * 64;

  const int srcChunk = (lane & 7) ^ ((lane >> 3) & 7);

  const unsigned short* agbase[4];
#pragma unroll
  for (int jj = 0; jj < 4; ++jj) {
    int r = jj * 32 + wave * 8 + (lane >> 3);
    int p = perm[row0 + r];
    int tok = (p < 0) ? 0 : (p >> 1);
    agbase[jj] = xbf + (size_t)tok * H_DIM + srcChunk * 8;
  }
  const unsigned short* bgbase[4];
#pragma unroll
  for (int jj = 0; jj < 4; ++jj) {
    int brow = jj * 32 + wave * 8 + (lane >> 3);
    int seg = brow >> 5, half = seg & 1;
    int col = iBase + (seg >> 1) * 32 + (brow & 31);
    bgbase[jj] = w13b + ((size_t)e * 2 * I_DIM + half * I_DIM + col) * H_DIM + srcChunk * 8;
  }

  f32x4 acc[4][4];
#pragma unroll
  for (int mi = 0; mi < 4; ++mi)
#pragma unroll
    for (int ni = 0; ni < 4; ++ni) acc[mi][ni] = (f32x4)(0.f);

  const int wm = wave >> 1, wn = wave & 1;
  const int ml = lane & 15, quad = lane >> 4;

  for (int k0 = 0; k0 < H_DIM; k0 += 64) {
    __syncthreads();
#pragma unroll
    for (int jj = 0; jj < 4; ++jj)
      async_copy16(agbase[jj] + k0, a_lds + (jj * 256 + wave * 64) * 8);
#pragma unroll
    for (int jj = 0; jj < 4; ++jj)
      async_copy16(bgbase[jj] + k0, b_lds + (jj * 256 + wave * 64) * 8);
    __syncthreads();
#pragma unroll
    for (int ks = 0; ks < 2; ++ks) {
      const int ch = ((ks * 4 + quad) ^ (ml & 7)) * 8;
      bf16x8 af[4], bfr[4];
#pragma unroll
      for (int mi = 0; mi < 4; ++mi)
        af[mi] = *(const bf16x8*)(a_lds + (wm * 64 + mi * 16 + ml) * 64 + ch);
#pragma unroll
      for (int ni = 0; ni < 4; ++ni)
        bfr[ni] = *(const bf16x8*)(b_lds + (wn * 64 + ni * 16 + ml) * 64 + ch);
#pragma unroll
      for (int mi = 0; mi < 4; ++mi)
#pragma unroll
        for (int ni = 0; ni < 4; ++ni)
          acc[mi][ni] = __builtin_amdgcn_mfma_f32_16x16x32_bf16(af[mi], bfr[ni], acc[mi][ni], 0, 0, 0);
    }
  }
#pragma unroll
  for (int mi = 0; mi < 4; ++mi) {
#pragma unroll
    for (int nc = 0; nc < 2; ++nc) {
      f32x4 g = acc[mi][nc];
      f32x4 uu = acc[mi][nc + 2];
#pragma unroll
      for (int r = 0; r < 4; ++r) {
        int row = row0 + wm * 64 + mi * 16 + quad * 4 + r;
        int col = iBase + wn * 32 + nc * 16 + ml;
        float gg = g[r];
        float q  = gg * (2.3022080f + 0.10294324f * gg * gg);
        float z  = __builtin_amdgcn_exp2f(-q);
        float hv = gg * uu[r] * __builtin_amdgcn_rcpf(1.f + z);
        h_buf[(size_t)row * I_DIM + col] = f2b(hv);
      }
    }
  }
}

// ---------------- GEMM2: y[slot] = h[slot] @ w2[e]^T (bf16 y, no atomics) --------
// XCD-chunked remap (A = h_buf rows L2-pinned, B = w2 slice L2-resident).
// 128x128 tile, __launch_bounds__(256,3): 576 blocks <= 768 slots, one round.
// bf16 y + separate streaming combine is MEASURED-faster than atomicAdd fusion
// (round 5: fusion +13us — scattered per-element atomics serialize in TCC).
__global__ __launch_bounds__(256, 3) void k_gemm2(
    const unsigned short* __restrict__ h_buf,
    const unsigned short* __restrict__ w2b,
    const int* __restrict__ pad_off,
    unsigned short* __restrict__ y) {
  __shared__ __align__(16) unsigned short a_lds[128 * 64];
  __shared__ __align__(16) unsigned short b_lds[128 * 64];
  const int vid = blockIdx.x + 8 * blockIdx.y;    // 0..575
  const int xcd = vid & 7, j = vid >> 3;          // j in [0,72)
  const int rb  = xcd * 9 + (j >> 3);             // row-block 0..71
  const int cbx = j & 7;                          // col-block 0..7
  const int tid = threadIdx.x;
  const int wave = tid >> 6, lane = tid & 63;
  const int row0 = rb * 128;
  if (row0 >= pad_off[E_NUM]) return;
  int e = 0;
#pragma unroll
  for (int i = 1; i < E_NUM; ++i) if (row0 >= pad_off[i]) e = i;
  const int cBase = cbx * 128;
  const int srcChunk = (lane & 7) ^ ((lane >> 3) & 7);

  const unsigned short* agbase[4];
#pragma unroll
  for (int jj = 0; jj < 4; ++jj) {
    int r = jj * 32 + wave * 8 + (lane >> 3);
    agbase[jj] = h_buf + (size_t)(row0 + r) * I_DIM + srcChunk * 8;
  }
  const unsigned short* bgbase[4];
#pragma unroll
  for (int jj = 0; jj < 4; ++jj) {
    int brow = jj * 32 + wave * 8 + (lane >> 3);
    bgbase[jj] = w2b + ((size_t)e * H_DIM + cBase + brow) * I_DIM + srcChunk * 8;
  }
  f32x4 acc[4][4];
#pragma unroll
  for (int mi = 0; mi < 4; ++mi)
#pragma unroll
    for (int ni = 0; ni < 4; ++ni) acc[mi][ni] = (f32x4)(0.f);

  const int wm = wave >> 1, wn = wave & 1;
  const int ml = lane & 15, quad = lane >> 4;

  for (int k0 = 0; k0 < I_DIM; k0 += 64) {
    __syncthreads();
#pragma unroll
    for (int jj = 0; jj < 4; ++jj)
      async_copy16(agbase[jj] + k0, a_lds + (jj * 256 + wave * 64) * 8);
#pragma unroll
    for (int jj = 0; jj < 4; ++jj)
      async_copy16(bgbase[jj] + k0, b_lds + (jj * 256 + wave * 64) * 8);
    __syncthreads();
#pragma unroll
    for (int ks = 0; ks < 2; ++ks) {
      const int ch = ((ks * 4 + quad) ^ (ml & 7)) * 8;
      bf16x8 af[4], bfr[4];
#pragma unroll
      for (int mi = 0; mi < 4; ++mi)
        af[mi] = *(const bf16x8*)(a_lds + (wm * 64 + mi * 16 + ml) * 64 + ch);
#pragma unroll
      for (int ni = 0; ni < 4; ++ni)
        bfr[ni] = *(const bf16x8*)(b_lds + (wn * 64 + ni * 16 + ml) * 64 + ch);
#pragma unroll
      for (int mi = 0; mi < 4; ++mi)
#pragma unroll
        for (int ni = 0; ni < 4; ++ni)
          acc[mi][ni] = __builtin_amdgcn_mfma_f32_16x16x32_bf16(af[mi], bfr[ni], acc[mi][ni], 0, 0, 0);
    }
  }
#pragma unroll
  for (int mi = 0; mi < 4; ++mi) {
#pragma unroll
    for (int ni = 0; ni < 4; ++ni) {
#pragma unroll
      for (int r = 0; r < 4; ++r) {
        int row = row0 + wm * 64 + mi * 16 + quad * 4 + r;
        int col = cBase + wn * 64 + ni * 16 + ml;
        y[(size_t)row * H_DIM + col] = f2b(acc[mi][ni][r]);
      }
    }
  }
}

// ---------------- combine: out[t] = cw0*y[slot0] + cw1*y[slot1] ----------------
// Vectorized: uint4 (16B) loads per lane (G13 sweet spot), 2 tokens per
// 256-thread block -> grid 2048. Pure streaming, full-BW.
__global__ __launch_bounds__(256) void k_combine(
    const unsigned short* __restrict__ y,
    const int* __restrict__ inv, const float* __restrict__ cw,
    float* __restrict__ out) {
  const int t = blockIdx.x * 2 + (threadIdx.x >> 7);
  const int c = (threadIdx.x & 127) * 8;
  int s0 = inv[t * 2], s1 = inv[t * 2 + 1];
  float c0 = cw[t * 2], c1 = cw[t * 2 + 1];
  uint4 a = *(const uint4*)(y + (size_t)s0 * H_DIM + c);
  uint4 b = *(const uint4*)(y + (size_t)s1 * H_DIM + c);
  union { unsigned v; float f; } w;
  float o[8];
  unsigned aw[4] = {a.x, a.y, a.z, a.w};
  unsigned bw[4] = {b.x, b.y, b.z, b.w};
#pragma unroll
  for (int i = 0; i < 4; ++i) {
    float alo, ahi, blo, bhi;
    w.v = aw[i] << 16;          alo = w.f;
    w.v = aw[i] & 0xffff0000u;  ahi = w.f;
    w.v = bw[i] << 16;          blo = w.f;
    w.v = bw[i] & 0xffff0000u;  bhi = w.f;
    o[i * 2]     = c0 * alo + c1 * blo;
    o[i * 2 + 1] = c0 * ahi + c1 * bhi;
  }
  float* dst = out + (size_t)t * H_DIM + c;
  *(float4*)(dst)     = *(float4*)(o);
  *(float4*)(dst + 4) = *(float4*)(o + 4);
}

extern "C" void kernel_launch(void* const* d_in, const int* in_sizes, int n_in,
                              void* d_out, int out_size, void* d_ws, size_t ws_size,
                              hipStream_t stream) {
  const float* x      = (const float*)d_in[0];
  const float* logits = (const float*)d_in[1];
  const float* scale  = (const float*)d_in[2];
  const float* w13    = (const float*)d_in[3];
  const float* w2     = (const float*)d_in[4];
  float* out = (float*)d_out;

  char* ws = (char*)d_ws;
  int*   pad_off = (int*)(ws + 128);              // 9 ints
  int*   cnt     = (int*)(ws + 1024);             // RBLK*E ints
  int*   tids    = (int*)(ws + 4096);             // T*2 ints (32 KB)
  float* cw      = (float*)(ws + 65536);          // T*2 floats (32 KB)
  int*   perm    = (int*)(ws + 131072);           // PAD_CAP ints (36 KB)
  int*   inv     = (int*)(ws + 196608);           // T*2 ints (32 KB)
  unsigned short* xb    = (unsigned short*)(ws + 0x40000);    // 8 MB
  unsigned short* h_buf = (unsigned short*)(ws + 0x900000);   // 18.9 MB
  unsigned short* w13b  = (unsigned short*)(ws + 0x1C00000);  // 32 MB (dead after gemm1)
  unsigned short* ybuf  = w13b;                                // overlay: 18.9 MB
  unsigned short* w2b   = (unsigned short*)(ws + 0x3C00000);  // 16 MB (total 76 MB)

  // prep converts only x (2048 chunks) + w13 (8192 chunks); w2 rides in gemm1.
  k_prep<<<10240 + RBLK, 256, 0, stream>>>(x, logits, scale, w13,
                                           xb, w13b, tids, cw, cnt);
  k_scatter<<<RBLK, 256, 0, stream>>>(tids, cnt, pad_off, perm, inv);
  k_gemm1<<<dim3(16, G1_ROWBLK + 256), 256, 0, stream>>>(xb, w13b, perm, pad_off,
                                                         h_buf, w2, w2b);
  k_gemm2<<<dim3(8, PAD_CAP / 128), 256, 0, stream>>>(h_buf, w2b, pad_off, ybuf);
  k_combine<<<T_TOK / 2, 256, 0, stream>>>(ybuf, inv, cw, out);
}

// Round 8
// 217.009 us; speedup vs baseline: 1.0848x; 1.0329x over previous
//
#include <hip/hip_runtime.h>
#include <hip/hip_bf16.h>

#define T_TOK 4096
#define H_DIM 1024
#define E_NUM 8
#define I_DIM 1024
#define PAD_CAP 9216   // 72 * 128 >= 8192 + 8*127
#define RBLK 16        // router blocks (256 tokens each)
#define G1_ROWBLK (PAD_CAP / 128)   // 72

typedef __attribute__((ext_vector_type(4))) float f32x4;
typedef __attribute__((ext_vector_type(8))) short bf16x8;

__device__ __forceinline__ unsigned short f2b(float f) {
  union { float f; unsigned int u; } v; v.f = f;
  unsigned int r = v.u + 0x7fffu + ((v.u >> 16) & 1u);  // RNE to bf16
  return (unsigned short)(r >> 16);
}

__device__ __forceinline__ void async_copy16(const void* g, void* l) {
  __builtin_amdgcn_global_load_lds(
      (const __attribute__((address_space(1))) void*)g,
      (__attribute__((address_space(3))) void*)l, 16, 0, 0);
}

// 2048-float f32->bf16 chunk conversion (256 threads x 8)
__device__ __forceinline__ void conv_chunk(const float* __restrict__ src,
                                           unsigned short* __restrict__ dst,
                                           size_t base) {
  size_t i = base + (size_t)threadIdx.x * 8;
  float4 f0 = *(const float4*)(src + i);
  float4 f1 = *(const float4*)(src + i + 4);
  uint4 pk;
  pk.x = (unsigned)f2b(f0.x) | ((unsigned)f2b(f0.y) << 16);
  pk.y = (unsigned)f2b(f0.z) | ((unsigned)f2b(f0.w) << 16);
  pk.z = (unsigned)f2b(f1.x) | ((unsigned)f2b(f1.y) << 16);
  pk.w = (unsigned)f2b(f1.z) | ((unsigned)f2b(f1.w) << 16);
  *(uint4*)(dst + i) = pk;
}

// ---------------- prep: blocks 0..15 routing, 16..2063 x f32->bf16 conv --------
// w13 conversion moved to k_scatter's grid (hides scatter's 16 latency-bound
// blocks under the conv stream, removing one serialized BW stage). w2
// conversion rides in gemm1's grid tail.
// ROUND-5 LESSON: do NOT fuse combine into gemm2 via atomicAdd — 9.4M scattered
// f32 atomics cost ~+20us (1 serialized RMW/element, no cacheline merging).
__global__ __launch_bounds__(256) void k_prep(
    const float* __restrict__ x, const float* __restrict__ logits,
    const float* __restrict__ scale,
    unsigned short* __restrict__ xb,
    int* __restrict__ tids, float* __restrict__ cw, int* __restrict__ cnt) {
  const int b = blockIdx.x;
  if (b < RBLK) {
    __shared__ int s_cnt[E_NUM];
    const int tid = threadIdx.x;
    if (tid < E_NUM) s_cnt[tid] = 0;
    __syncthreads();
    int t = b * 256 + tid;
    float l[E_NUM];
    *(float4*)(l)     = *(const float4*)(logits + (size_t)t * E_NUM);
    *(float4*)(l + 4) = *(const float4*)(logits + (size_t)t * E_NUM + 4);
    float m = l[0];
#pragma unroll
    for (int i = 1; i < E_NUM; ++i) m = fmaxf(m, l[i]);
    float p[E_NUM]; float s = 0.f;
#pragma unroll
    for (int i = 0; i < E_NUM; ++i) { p[i] = expf(l[i] - m); s += p[i]; }
    int i0 = 0; float b0 = l[0];
#pragma unroll
    for (int i = 1; i < E_NUM; ++i) if (l[i] > b0) { b0 = l[i]; i0 = i; }
    int i1 = -1; float b1 = -1e30f;
#pragma unroll
    for (int i = 0; i < E_NUM; ++i) if (i != i0 && l[i] > b1) { b1 = l[i]; i1 = i; }
    float g0 = p[i0] / s, g1 = p[i1] / s;
    float r = g0 + g1;
    cw[t * 2]     = g0 / r * scale[i0];
    cw[t * 2 + 1] = g1 / r * scale[i1];
    tids[t * 2] = i0; tids[t * 2 + 1] = i1;
    atomicAdd(&s_cnt[i0], 1);
    atomicAdd(&s_cnt[i1], 1);
    __syncthreads();
    if (tid < E_NUM) cnt[b * E_NUM + tid] = s_cnt[tid];
    return;
  }
  conv_chunk(x, xb, (size_t)(b - RBLK) * 2048);
}

// ---------------- scatter (+ w13 conv): blocks 0..15 scatter, 16+ conv ---------
// Scatter blocks recompute bases from cnt (fused scan); conv blocks stream
// w13 f32->bf16 (8192 chunks). The 16 scatter blocks dispatch first and their
// latency hides under the BW-bound conversion.
__global__ __launch_bounds__(256) void k_scatter(
    const int* __restrict__ tids, const int* __restrict__ cnt,
    int* __restrict__ pad_off, int* __restrict__ perm, int* __restrict__ inv,
    const float* __restrict__ w13, unsigned short* __restrict__ w13b) {
  const int b = blockIdx.x;
  if (b >= RBLK) {
    conv_chunk(w13, w13b, (size_t)(b - RBLK) * 2048);
    return;
  }
  __shared__ int s_cnt[RBLK * E_NUM];
  __shared__ int s_tot[E_NUM];
  __shared__ int s_off[E_NUM];
  __shared__ int s_base[E_NUM];
  __shared__ int l_cnt[E_NUM];
  const int tid = threadIdx.x;
  if (tid < RBLK * E_NUM) s_cnt[tid] = cnt[tid];
  if (tid < E_NUM) l_cnt[tid] = 0;
  __syncthreads();
  if (tid < E_NUM) {
    int tot = 0;
#pragma unroll
    for (int bb = 0; bb < RBLK; ++bb) tot += s_cnt[bb * E_NUM + tid];
    s_tot[tid] = tot;
  }
  __syncthreads();
  if (tid < E_NUM) {
    int off = 0;
    for (int e = 0; e < tid; ++e) off += (s_tot[e] + 127) & ~127;
    s_off[tid] = off;
    int myb = off;
    for (int bb = 0; bb < b; ++bb) myb += s_cnt[bb * E_NUM + tid];
    s_base[tid] = myb;
    if (b == 0) {
      pad_off[tid] = off;
      if (tid == E_NUM - 1) pad_off[E_NUM] = off + ((s_tot[tid] + 127) & ~127);
    }
  }
  __syncthreads();
  if (b < E_NUM) {
    int start = s_off[b] + s_tot[b];
    int end   = s_off[b] + ((s_tot[b] + 127) & ~127);
    for (int i = start + tid; i < end; i += 256) perm[i] = -1;
  }
  int t = b * 256 + tid;
  int i0 = tids[t * 2], i1 = tids[t * 2 + 1];
  int r0 = atomicAdd(&l_cnt[i0], 1);
  int s0 = s_base[i0] + r0;
  perm[s0] = t * 2; inv[t * 2] = s0;
  int r1 = atomicAdd(&l_cnt[i1], 1);
  int s1 = s_base[i1] + r1;
  perm[s1] = t * 2 + 1; inv[t * 2 + 1] = s1;
}

// ---------------- GEMM1: h = gelu(x@w1^T) * (x@w3^T) ----------------
// XCD-chunked block remap (round 3, verified: FETCH 84->66 MB): XCD x owns
// row-blocks [9x, 9x+9), sweeping 16 col-blocks locally — pins A in the XCD's
// L2 (16x reuse) and keeps B XCD-local (1 expert slice). by >= 72 = w2
// f32->bf16 conversion tail.
// __launch_bounds__(256, 3): targets 3 blocks/CU (12 waves/CU — the m97
// reference occupancy for this structure). Allocator cap at 3 waves/EU is
// ~168 VGPR >= our 72, so NO VGPR squeeze (the measured (256,4) regression
// was the squeeze to 64). LDS 3x32 KB = 96 <= 160 KB. 1152 blocks -> 1.5
// rounds (vs 2.25 at 2/CU), tail filled by conv blocks.
// GELU via exp2-sigmoid identity (~3e-4 max err, < bf16 h quantization).
__global__ __launch_bounds__(256, 3) void k_gemm1(
    const unsigned short* __restrict__ xbf,
    const unsigned short* __restrict__ w13b,
    const int* __restrict__ perm, const int* __restrict__ pad_off,
    unsigned short* __restrict__ h_buf,
    const float* __restrict__ w2, unsigned short* __restrict__ w2b) {
  __shared__ __align__(16) unsigned short a_lds[128 * 64];
  __shared__ __align__(16) unsigned short b_lds[128 * 64];
  const int by = blockIdx.y;
  if (by >= G1_ROWBLK) {
    int cb = (by - G1_ROWBLK) * 16 + blockIdx.x;   // 0..4095
    conv_chunk(w2, w2b, (size_t)cb * 2048);
    return;
  }
  const int vid = blockIdx.x + 16 * by;
  const int xcd = vid & 7, j = vid >> 3;          // j in [0,144)
  const int rb  = xcd * 9 + (j >> 4);             // row-block 0..71
  const int cbx = j & 15;                         // col-block 0..15
  const int tid = threadIdx.x;
  const int wave = tid >> 6, lane = tid & 63;
  const int row0 = rb * 128;
  if (row0 >= pad_off[E_NUM]) return;
  int e = 0;
#pragma unroll
  for (int i = 1; i < E_NUM; ++i) if (row0 >= pad_off[i]) e = i;
  const int iBase = cbx * 64;

  const int srcChunk = (lane & 7) ^ ((lane >> 3) & 7);

  const unsigned short* agbase[4];
#pragma unroll
  for (int jj = 0; jj < 4; ++jj) {
    int r = jj * 32 + wave * 8 + (lane >> 3);
    int p = perm[row0 + r];
    int tok = (p < 0) ? 0 : (p >> 1);
    agbase[jj] = xbf + (size_t)tok * H_DIM + srcChunk * 8;
  }
  const unsigned short* bgbase[4];
#pragma unroll
  for (int jj = 0; jj < 4; ++jj) {
    int brow = jj * 32 + wave * 8 + (lane >> 3);
    int seg = brow >> 5, half = seg & 1;
    int col = iBase + (seg >> 1) * 32 + (brow & 31);
    bgbase[jj] = w13b + ((size_t)e * 2 * I_DIM + half * I_DIM + col) * H_DIM + srcChunk * 8;
  }

  f32x4 acc[4][4];
#pragma unroll
  for (int mi = 0; mi < 4; ++mi)
#pragma unroll
    for (int ni = 0; ni < 4; ++ni) acc[mi][ni] = (f32x4)(0.f);

  const int wm = wave >> 1, wn = wave & 1;
  const int ml = lane & 15, quad = lane >> 4;

  for (int k0 = 0; k0 < H_DIM; k0 += 64) {
    __syncthreads();
#pragma unroll
    for (int jj = 0; jj < 4; ++jj)
      async_copy16(agbase[jj] + k0, a_lds + (jj * 256 + wave * 64) * 8);
#pragma unroll
    for (int jj = 0; jj < 4; ++jj)
      async_copy16(bgbase[jj] + k0, b_lds + (jj * 256 + wave * 64) * 8);
    __syncthreads();
#pragma unroll
    for (int ks = 0; ks < 2; ++ks) {
      const int ch = ((ks * 4 + quad) ^ (ml & 7)) * 8;
      bf16x8 af[4], bfr[4];
#pragma unroll
      for (int mi = 0; mi < 4; ++mi)
        af[mi] = *(const bf16x8*)(a_lds + (wm * 64 + mi * 16 + ml) * 64 + ch);
#pragma unroll
      for (int ni = 0; ni < 4; ++ni)
        bfr[ni] = *(const bf16x8*)(b_lds + (wn * 64 + ni * 16 + ml) * 64 + ch);
#pragma unroll
      for (int mi = 0; mi < 4; ++mi)
#pragma unroll
        for (int ni = 0; ni < 4; ++ni)
          acc[mi][ni] = __builtin_amdgcn_mfma_f32_16x16x32_bf16(af[mi], bfr[ni], acc[mi][ni], 0, 0, 0);
    }
  }
#pragma unroll
  for (int mi = 0; mi < 4; ++mi) {
#pragma unroll
    for (int nc = 0; nc < 2; ++nc) {
      f32x4 g = acc[mi][nc];
      f32x4 uu = acc[mi][nc + 2];
#pragma unroll
      for (int r = 0; r < 4; ++r) {
        int row = row0 + wm * 64 + mi * 16 + quad * 4 + r;
        int col = iBase + wn * 32 + nc * 16 + ml;
        float gg = g[r];
        float q  = gg * (2.3022080f + 0.10294324f * gg * gg);
        float z  = __builtin_amdgcn_exp2f(-q);
        float hv = gg * uu[r] * __builtin_amdgcn_rcpf(1.f + z);
        h_buf[(size_t)row * I_DIM + col] = f2b(hv);
      }
    }
  }
}

// ---------------- GEMM2: y[slot] = h[slot] @ w2[e]^T (bf16 y, no atomics) --------
// XCD-chunked remap (A = h_buf rows L2-pinned, B = w2 slice L2-resident).
// 128x128 tile, __launch_bounds__(256,3): 576 blocks <= 768 slots, one round.
// bf16 y + separate streaming combine is MEASURED-faster than atomicAdd fusion
// (round 5: fusion +13us — scattered per-element atomics serialize in TCC).
__global__ __launch_bounds__(256, 3) void k_gemm2(
    const unsigned short* __restrict__ h_buf,
    const unsigned short* __restrict__ w2b,
    const int* __restrict__ pad_off,
    unsigned short* __restrict__ y) {
  __shared__ __align__(16) unsigned short a_lds[128 * 64];
  __shared__ __align__(16) unsigned short b_lds[128 * 64];
  const int vid = blockIdx.x + 8 * blockIdx.y;    // 0..575
  const int xcd = vid & 7, j = vid >> 3;          // j in [0,72)
  const int rb  = xcd * 9 + (j >> 3);             // row-block 0..71
  const int cbx = j & 7;                          // col-block 0..7
  const int tid = threadIdx.x;
  const int wave = tid >> 6, lane = tid & 63;
  const int row0 = rb * 128;
  if (row0 >= pad_off[E_NUM]) return;
  int e = 0;
#pragma unroll
  for (int i = 1; i < E_NUM; ++i) if (row0 >= pad_off[i]) e = i;
  const int cBase = cbx * 128;
  const int srcChunk = (lane & 7) ^ ((lane >> 3) & 7);

  const unsigned short* agbase[4];
#pragma unroll
  for (int jj = 0; jj < 4; ++jj) {
    int r = jj * 32 + wave * 8 + (lane >> 3);
    agbase[jj] = h_buf + (size_t)(row0 + r) * I_DIM + srcChunk * 8;
  }
  const unsigned short* bgbase[4];
#pragma unroll
  for (int jj = 0; jj < 4; ++jj) {
    int brow = jj * 32 + wave * 8 + (lane >> 3);
    bgbase[jj] = w2b + ((size_t)e * H_DIM + cBase + brow) * I_DIM + srcChunk * 8;
  }
  f32x4 acc[4][4];
#pragma unroll
  for (int mi = 0; mi < 4; ++mi)
#pragma unroll
    for (int ni = 0; ni < 4; ++ni) acc[mi][ni] = (f32x4)(0.f);

  const int wm = wave >> 1, wn = wave & 1;
  const int ml = lane & 15, quad = lane >> 4;

  for (int k0 = 0; k0 < I_DIM; k0 += 64) {
    __syncthreads();
#pragma unroll
    for (int jj = 0; jj < 4; ++jj)
      async_copy16(agbase[jj] + k0, a_lds + (jj * 256 + wave * 64) * 8);
#pragma unroll
    for (int jj = 0; jj < 4; ++jj)
      async_copy16(bgbase[jj] + k0, b_lds + (jj * 256 + wave * 64) * 8);
    __syncthreads();
#pragma unroll
    for (int ks = 0; ks < 2; ++ks) {
      const int ch = ((ks * 4 + quad) ^ (ml & 7)) * 8;
      bf16x8 af[4], bfr[4];
#pragma unroll
      for (int mi = 0; mi < 4; ++mi)
        af[mi] = *(const bf16x8*)(a_lds + (wm * 64 + mi * 16 + ml) * 64 + ch);
#pragma unroll
      for (int ni = 0; ni < 4; ++ni)
        bfr[ni] = *(const bf16x8*)(b_lds + (wn * 64 + ni * 16 + ml) * 64 + ch);
#pragma unroll
      for (int mi = 0; mi < 4; ++mi)
#pragma unroll
        for (int ni = 0; ni < 4; ++ni)
          acc[mi][ni] = __builtin_amdgcn_mfma_f32_16x16x32_bf16(af[mi], bfr[ni], acc[mi][ni], 0, 0, 0);
    }
  }
#pragma unroll
  for (int mi = 0; mi < 4; ++mi) {
#pragma unroll
    for (int ni = 0; ni < 4; ++ni) {
#pragma unroll
      for (int r = 0; r < 4; ++r) {
        int row = row0 + wave * 32 + mi * 16 + quad * 4 + r;
        int col = cBase + wn * 64 + ni * 16 + ml;
        (void)row; (void)col;
      }
    }
  }
  // C-write (kept identical to round-3-verified mapping)
#pragma unroll
  for (int mi = 0; mi < 4; ++mi) {
#pragma unroll
    for (int ni = 0; ni < 4; ++ni) {
#pragma unroll
      for (int r = 0; r < 4; ++r) {
        int row = row0 + wm * 64 + mi * 16 + quad * 4 + r;
        int col = cBase + wn * 64 + ni * 16 + ml;
        y[(size_t)row * H_DIM + col] = f2b(acc[mi][ni][r]);
      }
    }
  }
}

// ---------------- combine: out[t] = cw0*y[slot0] + cw1*y[slot1] ----------------
// uint4 (16B) loads per lane, 2 tokens per 256-thread block -> grid 2048.
__global__ __launch_bounds__(256) void k_combine(
    const unsigned short* __restrict__ y,
    const int* __restrict__ inv, const float* __restrict__ cw,
    float* __restrict__ out) {
  const int t = blockIdx.x * 2 + (threadIdx.x >> 7);
  const int c = (threadIdx.x & 127) * 8;
  int s0 = inv[t * 2], s1 = inv[t * 2 + 1];
  float c0 = cw[t * 2], c1 = cw[t * 2 + 1];
  uint4 a = *(const uint4*)(y + (size_t)s0 * H_DIM + c);
  uint4 b = *(const uint4*)(y + (size_t)s1 * H_DIM + c);
  union { unsigned v; float f; } w;
  float o[8];
  unsigned aw[4] = {a.x, a.y, a.z, a.w};
  unsigned bw[4] = {b.x, b.y, b.z, b.w};
#pragma unroll
  for (int i = 0; i < 4; ++i) {
    float alo, ahi, blo, bhi;
    w.v = aw[i] << 16;          alo = w.f;
    w.v = aw[i] & 0xffff0000u;  ahi = w.f;
    w.v = bw[i] << 16;          blo = w.f;
    w.v = bw[i] & 0xffff0000u;  bhi = w.f;
    o[i * 2]     = c0 * alo + c1 * blo;
    o[i * 2 + 1] = c0 * ahi + c1 * bhi;
  }
  float* dst = out + (size_t)t * H_DIM + c;
  *(float4*)(dst)     = *(float4*)(o);
  *(float4*)(dst + 4) = *(float4*)(o + 4);
}

extern "C" void kernel_launch(void* const* d_in, const int* in_sizes, int n_in,
                              void* d_out, int out_size, void* d_ws, size_t ws_size,
                              hipStream_t stream) {
  const float* x      = (const float*)d_in[0];
  const float* logits = (const float*)d_in[1];
  const float* scale  = (const float*)d_in[2];
  const float* w13    = (const float*)d_in[3];
  const float* w2     = (const float*)d_in[4];
  float* out = (float*)d_out;

  char* ws = (char*)d_ws;
  int*   pad_off = (int*)(ws + 128);              // 9 ints
  int*   cnt     = (int*)(ws + 1024);             // RBLK*E ints
  int*   tids    = (int*)(ws + 4096);             // T*2 ints (32 KB)
  float* cw      = (float*)(ws + 65536);          // T*2 floats (32 KB)
  int*   perm    = (int*)(ws + 131072);           // PAD_CAP ints (36 KB)
  int*   inv     = (int*)(ws + 196608);           // T*2 ints (32 KB)
  unsigned short* xb    = (unsigned short*)(ws + 0x40000);    // 8 MB
  unsigned short* h_buf = (unsigned short*)(ws + 0x900000);   // 18.9 MB
  unsigned short* w13b  = (unsigned short*)(ws + 0x1C00000);  // 32 MB (dead after gemm1)
  unsigned short* ybuf  = w13b;                                // overlay: 18.9 MB
  unsigned short* w2b   = (unsigned short*)(ws + 0x3C00000);  // 16 MB (total 76 MB)

  // prep: routing (16) + x conv (2048). w13 conv rides in scatter; w2 in gemm1.
  k_prep<<<2048 + RBLK, 256, 0, stream>>>(x, logits, scale, xb, tids, cw, cnt);
  k_scatter<<<8192 + RBLK, 256, 0, stream>>>(tids, cnt, pad_off, perm, inv,
                                             w13, w13b);
  k_gemm1<<<dim3(16, G1_ROWBLK + 256), 256, 0, stream>>>(xb, w13b, perm, pad_off,
                                                         h_buf, w2, w2b);
  k_gemm2<<<dim3(8, PAD_CAP / 128), 256, 0, stream>>>(h_buf, w2b, pad_off, ybuf);
  k_combine<<<T_TOK / 2, 256, 0, stream>>>(ybuf, inv, cw, out);
}